// Round 8
// baseline (282.180 us; speedup 1.0000x reference)
//
#include <hip/hip_runtime.h>
#include <hip/hip_bf16.h>

// AttentionFlow, T=8192 J=1024 D2=512, fp32 in/out.
// Split-bf16 MFMA path: x = hi + lo (bf16 each); A@B ~= Ahi@Bhi + Ahi@Blo + Alo@Bhi.
//   S    = cdot[t] + qdot[j] + ctx @ (qry*wm)^T + Wb        (8192x1024, fp32 in ws)
//   P    = exp(S - rowmax); l = rowsum(P); c2q = (P@qry)/l
//   q2c  = rowmax(S) @ ctx
//   G    = [ctx | c2q | ctx*c2q | ctx*q2c]                  (8192x2048)
// R7: retiled both GEMMs to 1024 blocks (4 blocks/CU; was 512=2/CU,
// Occupancy 20%, MfmaUtil 10% -> latency-bound). gemm1: 128x64, gemm2:
// 64x64. Swizzle now groups same-bm blocks (shared 256KB A/P panel) within
// an XCD chunk for L2 reuse (FETCH was 140MB vs ~50 ideal).

typedef unsigned short u16;
typedef __attribute__((ext_vector_type(8))) short short8;
typedef __attribute__((ext_vector_type(8))) unsigned short u16x8;
typedef __attribute__((ext_vector_type(4))) float f32x4;

#define T_ROWS 8192
#define J_ROWS 1024
#define D2 512
#define G_LD 2048
#define PSTR 2048   // P row stride in u16 (P packed inside fp32 S rows)

__device__ __forceinline__ float bf2f(u16 u) {
    return __uint_as_float((unsigned)u << 16);
}
__device__ __forceinline__ void bsplit(float v, u16& h, u16& l) {
    __hip_bfloat16 bh = __float2bfloat16(v);
    h = __builtin_bit_cast(u16, bh);
    float r = v - __uint_as_float((unsigned)h << 16);
    __hip_bfloat16 bl = __float2bfloat16(r);
    l = __builtin_bit_cast(u16, bl);
}

#define GLDS16(g, l) __builtin_amdgcn_global_load_lds( \
    (const __attribute__((address_space(1))) void*)(g), \
    (__attribute__((address_space(3))) void*)(l), 16, 0, 0)

// ------- split ctx into bf16 hi/lo + cdot[t] = ctx[t]·wc (one wave/row) ----
__global__ __launch_bounds__(256) void split_ctx_kernel(
        const float* __restrict__ ctx, const float* __restrict__ Ww,
        u16* __restrict__ hi, u16* __restrict__ lo, float* __restrict__ cdot) {
    int t = blockIdx.x * 4 + (threadIdx.x >> 6);
    int lane = threadIdx.x & 63;
    const float* row = ctx + (size_t)t * D2 + lane * 8;
    float4 r0 = *(const float4*)row;
    float4 r1 = *(const float4*)(row + 4);
    float4 w0 = *(const float4*)(Ww + lane * 8);
    float4 w1 = *(const float4*)(Ww + lane * 8 + 4);
    float v[8] = {r0.x, r0.y, r0.z, r0.w, r1.x, r1.y, r1.z, r1.w};
    u16x8 h, l;
    #pragma unroll
    for (int i = 0; i < 8; ++i) {
        u16 hh, ll;
        bsplit(v[i], hh, ll);
        h[i] = hh; l[i] = ll;
    }
    size_t o = (size_t)t * D2 + lane * 8;
    *(u16x8*)(hi + o) = h;
    *(u16x8*)(lo + o) = l;
    float s = r0.x * w0.x + r0.y * w0.y + r0.z * w0.z + r0.w * w0.w
            + r1.x * w1.x + r1.y * w1.y + r1.z * w1.z + r1.w * w1.w;
    #pragma unroll
    for (int off = 32; off; off >>= 1) s += __shfl_xor(s, off);
    if (lane == 0) cdot[t] = s;
}

// ---------------- split qry*wm (row-major) + plain qry transposed ----------
__global__ __launch_bounds__(256) void split_q_kernel(
        const float* __restrict__ qry, const float* __restrict__ Ww,
        u16* __restrict__ qmh, u16* __restrict__ qml,
        u16* __restrict__ qth, u16* __restrict__ qtl) {
    __shared__ float tile[32][33];
    const float* wm = Ww + 2 * D2;
    int bj = blockIdx.x * 32, bd = blockIdx.y * 32;
    int tx = threadIdx.x & 31, ty = threadIdx.x >> 5;   // ty: 0..7
    #pragma unroll
    for (int r = 0; r < 4; ++r) {
        int j = ty * 4 + r;
        float v = qry[(size_t)(bj + j) * D2 + bd + tx];
        tile[j][tx] = v;
        u16 h, l;
        bsplit(v * wm[bd + tx], h, l);
        size_t o = (size_t)(bj + j) * D2 + bd + tx;
        qmh[o] = h; qml[o] = l;
    }
    __syncthreads();
    #pragma unroll
    for (int r = 0; r < 4; ++r) {
        int d = ty * 4 + r;
        float v = tile[tx][d];      // qry[bj+tx][bd+d]
        u16 h, l;
        bsplit(v, h, l);
        size_t o = (size_t)(bd + d) * J_ROWS + bj + tx;
        qth[o] = h; qtl[o] = l;
    }
}

// ---------------- qdot[j] = qry[j]·wq (one wave/row, exact fp32) -----------
__global__ __launch_bounds__(256) void qdot_kernel(
        const float* __restrict__ qry, const float* __restrict__ Ww,
        float* __restrict__ qdot) {
    int j = blockIdx.x * 4 + (threadIdx.x >> 6);
    int lane = threadIdx.x & 63;
    const float* row = qry + (size_t)j * D2 + lane * 8;
    const float* w = Ww + D2 + lane * 8;
    float4 r0 = *(const float4*)row;
    float4 r1 = *(const float4*)(row + 4);
    float4 w0 = *(const float4*)w;
    float4 w1 = *(const float4*)(w + 4);
    float s = r0.x * w0.x + r0.y * w0.y + r0.z * w0.z + r0.w * w0.w
            + r1.x * w1.x + r1.y * w1.y + r1.z * w1.z + r1.w * w1.w;
    #pragma unroll
    for (int off = 32; off; off >>= 1) s += __shfl_xor(s, off);
    if (lane == 0) qdot[j] = s;
}

// ---------------- GEMM1 (MFMA split-bf16): S = A@B^T + dots + Wb (fp32) ----
// M=8192 N=1024 K=512. BM=128 BN=64, 4 waves 2x2 (wave: 64x32), BK=32.
// grid: 1024 blocks = 4/CU, XCD-swizzled; bn = s&15 (fast), bm = s>>4 so
// same-bm blocks (sharing the 256KB ctx panel) are adjacent within an XCD.
__global__ __launch_bounds__(256) void gemm1_mfma(
        const u16* __restrict__ Ahi, const u16* __restrict__ Alo,
        const u16* __restrict__ Bhi, const u16* __restrict__ Blo,
        const float* __restrict__ cdot, const float* __restrict__ qdot,
        const float* __restrict__ Wb, float* __restrict__ Sf) {
    __shared__ u16 ldsA[2][4096];   // ctx hi/lo: [ksub=4][row=128][k0=8]
    __shared__ u16 ldsB[2][2048];   // qm  hi/lo: [ksub=4][row= 64][k0=8]
    const int tid = threadIdx.x;
    const int wid = tid >> 6, lane = tid & 63;
    const int wr = wid >> 1, wc = wid & 1;
    int flat = blockIdx.x;
    int s = (flat & 7) * 128 + (flat >> 3);      // 1024 blocks, bijective
    const int bn = s & 15, bm = s >> 4;

    f32x4 acc[4][2];
    #pragma unroll
    for (int mt = 0; mt < 4; ++mt)
        #pragma unroll
        for (int nt = 0; nt < 2; ++nt) acc[mt][nt] = (f32x4)0.0f;

    const u16* sg;
    u16* lb;
    if (wid == 0)      { sg = Ahi + (size_t)bm * 128 * D2; lb = &ldsA[0][0]; }
    else if (wid == 1) { sg = Alo + (size_t)bm * 128 * D2; lb = &ldsA[1][0]; }
    else if (wid == 2) { sg = Bhi + (size_t)bn * 64 * D2;  lb = &ldsB[0][0]; }
    else               { sg = Blo + (size_t)bn * 64 * D2;  lb = &ldsB[1][0]; }
    sg += (size_t)lane * D2;

    const int fr = lane & 15;
    const int ksub = lane >> 4;

    // A waves: 8 chunks (rows (c&1)*64+lane, ksub c>>1) -> lb + c*512.
    // B waves: 4 chunks (row lane, ksub c)              -> lb + c*512.
    #define STAGE1(kb_) do {                                                  \
        if (wid < 2) {                                                        \
            _Pragma("unroll")                                                 \
            for (int c = 0; c < 8; ++c)                                       \
                GLDS16(sg + (size_t)(c & 1) * 64 * D2 + (kb_) + (c >> 1) * 8, \
                       lb + c * 512);                                         \
        } else {                                                              \
            _Pragma("unroll")                                                 \
            for (int c = 0; c < 4; ++c)                                       \
                GLDS16(sg + (kb_) + c * 8, lb + c * 512);                     \
        }                                                                     \
    } while (0)

    STAGE1(0);
    __syncthreads();

    for (int kb = 0; kb < D2; kb += 32) {
        short8 ah[4], al[4], bh[2], bl[2];
        #pragma unroll
        for (int t = 0; t < 4; ++t) {
            int ra = wr * 64 + t * 16 + fr;
            ah[t] = *(const short8*)&ldsA[0][ksub * 1024 + ra * 8];
            al[t] = *(const short8*)&ldsA[1][ksub * 1024 + ra * 8];
        }
        #pragma unroll
        for (int t = 0; t < 2; ++t) {
            int rb = wc * 32 + t * 16 + fr;
            bh[t] = *(const short8*)&ldsB[0][ksub * 512 + rb * 8];
            bl[t] = *(const short8*)&ldsB[1][ksub * 512 + rb * 8];
        }
        __syncthreads();
        if (kb + 32 < D2) STAGE1(kb + 32);
        #pragma unroll
        for (int mt = 0; mt < 4; ++mt)
            #pragma unroll
            for (int nt = 0; nt < 2; ++nt) {
                acc[mt][nt] = __builtin_amdgcn_mfma_f32_16x16x32_bf16(ah[mt], bh[nt], acc[mt][nt], 0, 0, 0);
                acc[mt][nt] = __builtin_amdgcn_mfma_f32_16x16x32_bf16(ah[mt], bl[nt], acc[mt][nt], 0, 0, 0);
                acc[mt][nt] = __builtin_amdgcn_mfma_f32_16x16x32_bf16(al[mt], bh[nt], acc[mt][nt], 0, 0, 0);
            }
        __syncthreads();
    }
    #undef STAGE1

    float wb = Wb[0];
    #pragma unroll
    for (int mt = 0; mt < 4; ++mt) {
        int rowb = bm * 128 + wr * 64 + mt * 16 + (lane >> 4) * 4;
        float cd[4];
        #pragma unroll
        for (int r = 0; r < 4; ++r) cd[r] = cdot[rowb + r] + wb;
        #pragma unroll
        for (int nt = 0; nt < 2; ++nt) {
            int col = bn * 64 + wc * 32 + nt * 16 + fr;
            float qd = qdot[col];
            #pragma unroll
            for (int r = 0; r < 4; ++r)
                Sf[(size_t)(rowb + r) * J_ROWS + col] = acc[mt][nt][r] + cd[r] + qd;
        }
    }
}

// ------- softmax: read fp32 S row, write P hi/lo bf16 in place; m, l -------
__global__ __launch_bounds__(256) void softmax_kernel(
        float* S, float* m_out, float* l_out) {
    int t = blockIdx.x * 4 + (threadIdx.x >> 6);
    int lane = threadIdx.x & 63;
    float* rowf = S + (size_t)t * J_ROWS;
    float s[16];
    #pragma unroll
    for (int q = 0; q < 4; ++q) {
        float4 v = *(const float4*)(rowf + lane * 16 + q * 4);
        s[q * 4 + 0] = v.x; s[q * 4 + 1] = v.y;
        s[q * 4 + 2] = v.z; s[q * 4 + 3] = v.w;
    }
    float mx = s[0];
    #pragma unroll
    for (int i = 1; i < 16; ++i) mx = fmaxf(mx, s[i]);
    #pragma unroll
    for (int off = 32; off; off >>= 1) mx = fmaxf(mx, __shfl_xor(mx, off));
    float sum = 0.f;
    #pragma unroll
    for (int i = 0; i < 16; ++i) { s[i] = __expf(s[i] - mx); sum += s[i]; }
    #pragma unroll
    for (int off = 32; off; off >>= 1) sum += __shfl_xor(sum, off);
    u16x8 ph[2], pl[2];
    #pragma unroll
    for (int i = 0; i < 16; ++i) {
        u16 h, l; bsplit(s[i], h, l);
        ph[i >> 3][i & 7] = h; pl[i >> 3][i & 7] = l;
    }
    u16* rowp = (u16*)rowf;
    *(u16x8*)(rowp + lane * 16)          = ph[0];
    *(u16x8*)(rowp + lane * 16 + 8)      = ph[1];
    *(u16x8*)(rowp + 1024 + lane * 16)     = pl[0];
    *(u16x8*)(rowp + 1024 + lane * 16 + 8) = pl[1];
    if (lane == 0) { m_out[t] = mx; l_out[t] = sum; }
}

// ---------------- q2c[d] = sum_t m[t]*ctx[t,d] -----------------------------
__global__ __launch_bounds__(256) void q2c_kernel(
        const float* __restrict__ ctx, const float* __restrict__ m,
        float* __restrict__ q2c) {
    int d0 = threadIdx.x * 2;
    int tbase = blockIdx.x * 64;
    float ax = 0.f, ay = 0.f;
    for (int r = 0; r < 64; ++r) {
        int t = tbase + r;
        float b = m[t];
        float2 c = *(const float2*)(ctx + (size_t)t * D2 + d0);
        ax += b * c.x;
        ay += b * c.y;
    }
    atomicAdd(&q2c[d0], ax);
    atomicAdd(&q2c[d0 + 1], ay);
}

// ---------------- GEMM2 (MFMA split-bf16): c2q=(P@qry)/l; writes ALL of G --
// M=8192 N=512 K=1024. BM=64 BN=64, 4 waves 2x2 (wave: 32x32), BK=32.
// grid: 1024 blocks = 4/CU, XCD-swizzled; bn = s&7 (fast), bm = s>>3 so the
// 8 bn-blocks sharing a 256KB P panel are adjacent within an XCD.
__global__ __launch_bounds__(256) void gemm2_mfma(
        const u16* __restrict__ P, const u16* __restrict__ Qth,
        const u16* __restrict__ Qtl, const float* __restrict__ l_in,
        const float* __restrict__ ctx, const float* __restrict__ q2c,
        float* __restrict__ G) {
    __shared__ u16 ldsA[2][2048];   // P hi/lo:    [ksub=4][row=64][k0=8]
    __shared__ u16 ldsB[2][2048];   // qry^T hi/lo:[ksub=4][row=64][k0=8]
    const int tid = threadIdx.x;
    const int wid = tid >> 6, lane = tid & 63;
    const int wr = wid >> 1, wc = wid & 1;
    int flat = blockIdx.x;
    int s = (flat & 7) * 128 + (flat >> 3);      // 1024 blocks, bijective
    const int bn = s & 7, bm = s >> 3;

    f32x4 acc[2][2];
    #pragma unroll
    for (int mt = 0; mt < 2; ++mt)
        #pragma unroll
        for (int nt = 0; nt < 2; ++nt) acc[mt][nt] = (f32x4)0.0f;

    const u16* sg;
    u16* lb;
    if (wid == 0)      { sg = P + (size_t)bm * 64 * PSTR + (size_t)lane * PSTR;        lb = &ldsA[0][0]; }
    else if (wid == 1) { sg = P + (size_t)bm * 64 * PSTR + 1024 + (size_t)lane * PSTR; lb = &ldsA[1][0]; }
    else if (wid == 2) { sg = Qth + (size_t)bn * 64 * J_ROWS + (size_t)lane * J_ROWS;  lb = &ldsB[0][0]; }
    else               { sg = Qtl + (size_t)bn * 64 * J_ROWS + (size_t)lane * J_ROWS;  lb = &ldsB[1][0]; }

    const int fr = lane & 15;
    const int ksub = lane >> 4;

    // every wave: 4 chunks (row lane, ksub c) -> lb + c*512
    #define STAGE2(kb_) do {                                                  \
        _Pragma("unroll")                                                     \
        for (int c = 0; c < 4; ++c)                                           \
            GLDS16(sg + (kb_) + c * 8, lb + c * 512);                         \
    } while (0)

    STAGE2(0);
    __syncthreads();

    for (int kb = 0; kb < J_ROWS; kb += 32) {
        short8 ah[2], al[2], bh[2], bl[2];
        #pragma unroll
        for (int t = 0; t < 2; ++t) {
            int ra = wr * 32 + t * 16 + fr;
            ah[t] = *(const short8*)&ldsA[0][ksub * 512 + ra * 8];
            al[t] = *(const short8*)&ldsA[1][ksub * 512 + ra * 8];
            int rb = wc * 32 + t * 16 + fr;
            bh[t] = *(const short8*)&ldsB[0][ksub * 512 + rb * 8];
            bl[t] = *(const short8*)&ldsB[1][ksub * 512 + rb * 8];
        }
        __syncthreads();
        if (kb + 32 < J_ROWS) STAGE2(kb + 32);
        #pragma unroll
        for (int mt = 0; mt < 2; ++mt)
            #pragma unroll
            for (int nt = 0; nt < 2; ++nt) {
                acc[mt][nt] = __builtin_amdgcn_mfma_f32_16x16x32_bf16(ah[mt], bh[nt], acc[mt][nt], 0, 0, 0);
                acc[mt][nt] = __builtin_amdgcn_mfma_f32_16x16x32_bf16(ah[mt], bl[nt], acc[mt][nt], 0, 0, 0);
                acc[mt][nt] = __builtin_amdgcn_mfma_f32_16x16x32_bf16(al[mt], bh[nt], acc[mt][nt], 0, 0, 0);
            }
        __syncthreads();
    }
    #undef STAGE2

    #pragma unroll
    for (int mt = 0; mt < 2; ++mt) {
        int rowb = bm * 64 + wr * 32 + mt * 16 + (lane >> 4) * 4;
        float rl4[4];
        #pragma unroll
        for (int r = 0; r < 4; ++r) rl4[r] = 1.0f / l_in[rowb + r];
        #pragma unroll
        for (int nt = 0; nt < 2; ++nt) {
            int d = bn * 64 + wc * 32 + nt * 16 + fr;
            float qc = q2c[d];
            #pragma unroll
            for (int r = 0; r < 4; ++r) {
                int row = rowb + r;
                float v = acc[mt][nt][r] * rl4[r];
                float c = ctx[(size_t)row * D2 + d];
                float* gr = G + (size_t)row * G_LD;
                gr[d] = c;
                gr[512 + d] = v;
                gr[1024 + d] = c * v;
                gr[1536 + d] = c * qc;
            }
        }
    }
}

extern "C" void kernel_launch(void* const* d_in, const int* in_sizes, int n_in,
                              void* d_out, int out_size, void* d_ws, size_t ws_size,
                              hipStream_t stream) {
    const float* ctx = (const float*)d_in[0];
    const float* qry = (const float*)d_in[1];
    const float* Ww  = (const float*)d_in[2];
    const float* Wb  = (const float*)d_in[3];
    float* G = (float*)d_out;

    const size_t MB = 1ull << 20;
    char* p = (char*)d_ws;
    float* Sf = (float*)p; p += 32 * MB;  // S fp32; later P hi/lo in place
    u16* ctxh = (u16*)p; p += 8 * MB;
    u16* ctxl = (u16*)p; p += 8 * MB;
    u16* qmh  = (u16*)p; p += 1 * MB;     // (qry*wm) hi, [J][D2]
    u16* qml  = (u16*)p; p += 1 * MB;
    u16* qth  = (u16*)p; p += 1 * MB;     // qry^T hi, [D2][J]
    u16* qtl  = (u16*)p; p += 1 * MB;
    float* cdot = (float*)p; p += T_ROWS * 4;
    float* qdot = (float*)p; p += J_ROWS * 4;
    float* mrow = (float*)p; p += T_ROWS * 4;
    float* lrow = (float*)p; p += T_ROWS * 4;
    float* q2c  = (float*)p; p += D2 * 4;

    (void)hipMemsetAsync(q2c, 0, D2 * sizeof(float), stream);

    split_ctx_kernel<<<T_ROWS / 4, 256, 0, stream>>>(ctx, Ww, ctxh, ctxl, cdot);
    split_q_kernel<<<dim3(J_ROWS / 32, D2 / 32), 256, 0, stream>>>(qry, Ww, qmh, qml, qth, qtl);
    qdot_kernel<<<J_ROWS / 4, 256, 0, stream>>>(qry, Ww, qdot);

    gemm1_mfma<<<1024, 256, 0, stream>>>(ctxh, ctxl, qmh, qml, cdot, qdot, Wb, Sf);
    softmax_kernel<<<T_ROWS / 4, 256, 0, stream>>>(Sf, mrow, lrow);
    q2c_kernel<<<T_ROWS / 64, 256, 0, stream>>>(ctx, mrow, q2c);
    gemm2_mfma<<<1024, 256, 0, stream>>>((u16*)Sf, qth, qtl, lrow, ctx, q2c, G);
}

// Round 10
// 188.350 us; speedup vs baseline: 1.4982x; 1.4982x over previous
//
#include <hip/hip_runtime.h>
#include <hip/hip_bf16.h>

// AttentionFlow, T=8192 J=1024 D2=512, fp32 in/out.
// Split-bf16 MFMA path: x = hi + lo (bf16 each); A@B ~= Ahi@Bhi + Ahi@Blo + Alo@Bhi.
//   S    = cdot[t] + qdot[j] + ctx @ (qry*wm)^T + Wb        (8192x1024, fp32 in ws)
//   P    = exp(S - rowmax); l = rowsum(P); c2q = (P@qry)/l
//   q2c  = rowmax(S) @ ctx
//   G    = [ctx | c2q | ctx*c2q | ctx*q2c]                  (8192x2048)
// R9 (resubmit; prior round timed out before running): staging restructured
// from 64-lines/instr (lane-per-row) to 16-lines/instr (16 rows x 4 lanes
// sharing a 64B row segment) -- theory: VMEM line-request rate was the
// invisible bottleneck (all sampled counters low, duration invariant under
// occupancy). LDS is [row][32k] linear with source-side XOR pre-swizzle
// slot'=c^((lane>>3)&3) and the SAME XOR on ds_read (both-sides-or-neither),
// keeping reads bank-uniform. Desk-verified: content k-slot == ksub after
// the XOR pair cancels; 8 dword-accesses/bank/wave = data-volume minimum.

typedef unsigned short u16;
typedef __attribute__((ext_vector_type(8))) short short8;
typedef __attribute__((ext_vector_type(8))) unsigned short u16x8;
typedef __attribute__((ext_vector_type(4))) float f32x4;

#define T_ROWS 8192
#define J_ROWS 1024
#define D2 512
#define G_LD 2048
#define PSTR 2048   // P row stride in u16 (P packed inside fp32 S rows)

__device__ __forceinline__ float bf2f(u16 u) {
    return __uint_as_float((unsigned)u << 16);
}
__device__ __forceinline__ void bsplit(float v, u16& h, u16& l) {
    __hip_bfloat16 bh = __float2bfloat16(v);
    h = __builtin_bit_cast(u16, bh);
    float r = v - __uint_as_float((unsigned)h << 16);
    __hip_bfloat16 bl = __float2bfloat16(r);
    l = __builtin_bit_cast(u16, bl);
}

#define GLDS16(g, l) __builtin_amdgcn_global_load_lds( \
    (const __attribute__((address_space(1))) void*)(g), \
    (__attribute__((address_space(3))) void*)(l), 16, 0, 0)

// ------- split ctx into bf16 hi/lo + cdot[t] = ctx[t]·wc (one wave/row) ----
__global__ __launch_bounds__(256) void split_ctx_kernel(
        const float* __restrict__ ctx, const float* __restrict__ Ww,
        u16* __restrict__ hi, u16* __restrict__ lo, float* __restrict__ cdot) {
    int t = blockIdx.x * 4 + (threadIdx.x >> 6);
    int lane = threadIdx.x & 63;
    const float* row = ctx + (size_t)t * D2 + lane * 8;
    float4 r0 = *(const float4*)row;
    float4 r1 = *(const float4*)(row + 4);
    float4 w0 = *(const float4*)(Ww + lane * 8);
    float4 w1 = *(const float4*)(Ww + lane * 8 + 4);
    float v[8] = {r0.x, r0.y, r0.z, r0.w, r1.x, r1.y, r1.z, r1.w};
    u16x8 h, l;
    #pragma unroll
    for (int i = 0; i < 8; ++i) {
        u16 hh, ll;
        bsplit(v[i], hh, ll);
        h[i] = hh; l[i] = ll;
    }
    size_t o = (size_t)t * D2 + lane * 8;
    *(u16x8*)(hi + o) = h;
    *(u16x8*)(lo + o) = l;
    float s = r0.x * w0.x + r0.y * w0.y + r0.z * w0.z + r0.w * w0.w
            + r1.x * w1.x + r1.y * w1.y + r1.z * w1.z + r1.w * w1.w;
    #pragma unroll
    for (int off = 32; off; off >>= 1) s += __shfl_xor(s, off);
    if (lane == 0) cdot[t] = s;
}

// ---------------- split qry*wm (row-major) + plain qry transposed ----------
__global__ __launch_bounds__(256) void split_q_kernel(
        const float* __restrict__ qry, const float* __restrict__ Ww,
        u16* __restrict__ qmh, u16* __restrict__ qml,
        u16* __restrict__ qth, u16* __restrict__ qtl) {
    __shared__ float tile[32][33];
    const float* wm = Ww + 2 * D2;
    int bj = blockIdx.x * 32, bd = blockIdx.y * 32;
    int tx = threadIdx.x & 31, ty = threadIdx.x >> 5;   // ty: 0..7
    #pragma unroll
    for (int r = 0; r < 4; ++r) {
        int j = ty * 4 + r;
        float v = qry[(size_t)(bj + j) * D2 + bd + tx];
        tile[j][tx] = v;
        u16 h, l;
        bsplit(v * wm[bd + tx], h, l);
        size_t o = (size_t)(bj + j) * D2 + bd + tx;
        qmh[o] = h; qml[o] = l;
    }
    __syncthreads();
    #pragma unroll
    for (int r = 0; r < 4; ++r) {
        int d = ty * 4 + r;
        float v = tile[tx][d];      // qry[bj+tx][bd+d]
        u16 h, l;
        bsplit(v, h, l);
        size_t o = (size_t)(bd + d) * J_ROWS + bj + tx;
        qth[o] = h; qtl[o] = l;
    }
}

// ---------------- qdot[j] = qry[j]·wq (one wave/row, exact fp32) -----------
__global__ __launch_bounds__(256) void qdot_kernel(
        const float* __restrict__ qry, const float* __restrict__ Ww,
        float* __restrict__ qdot) {
    int j = blockIdx.x * 4 + (threadIdx.x >> 6);
    int lane = threadIdx.x & 63;
    const float* row = qry + (size_t)j * D2 + lane * 8;
    const float* w = Ww + D2 + lane * 8;
    float4 r0 = *(const float4*)row;
    float4 r1 = *(const float4*)(row + 4);
    float4 w0 = *(const float4*)w;
    float4 w1 = *(const float4*)(w + 4);
    float s = r0.x * w0.x + r0.y * w0.y + r0.z * w0.z + r0.w * w0.w
            + r1.x * w1.x + r1.y * w1.y + r1.z * w1.z + r1.w * w1.w;
    #pragma unroll
    for (int off = 32; off; off >>= 1) s += __shfl_xor(s, off);
    if (lane == 0) qdot[j] = s;
}

// ---------------- GEMM1 (MFMA split-bf16): S = A@B^T + dots + Wb (fp32) ----
// M=8192 N=1024 K=512. BM=128 BN=64, 4 waves 2x2 (wave: 64x32), BK=32.
// grid: 1024 blocks = 4/CU, XCD-swizzled; bn fast so same-bm blocks share an
// XCD's L2 panel. Staging: 16 rows x 4 lanes/row per instr (16 lines).
__global__ __launch_bounds__(256) void gemm1_mfma(
        const u16* __restrict__ Ahi, const u16* __restrict__ Alo,
        const u16* __restrict__ Bhi, const u16* __restrict__ Blo,
        const float* __restrict__ cdot, const float* __restrict__ qdot,
        const float* __restrict__ Wb, float* __restrict__ Sf) {
    __shared__ u16 ldsA[2][4096];   // ctx hi/lo: [row=128][32k], 64B rows, XOR slots
    __shared__ u16 ldsB[2][2048];   // qm  hi/lo: [row= 64][32k]
    const int tid = threadIdx.x;
    const int wid = tid >> 6, lane = tid & 63;
    const int wr = wid >> 1, wc = wid & 1;
    int flat = blockIdx.x;
    int s = (flat & 7) * 128 + (flat >> 3);      // 1024 blocks, bijective
    const int bn = s & 15, bm = s >> 4;

    f32x4 acc[4][2];
    #pragma unroll
    for (int mt = 0; mt < 4; ++mt)
        #pragma unroll
        for (int nt = 0; nt < 2; ++nt) acc[mt][nt] = (f32x4)0.0f;

    // staging address: lane covers row (lane>>2), k-chunk (lane&3)^((lane>>3)&3)
    const int srow = lane >> 2;
    const int csw  = (lane & 3) ^ ((lane >> 3) & 3);
    const u16* sg;
    u16* lb;
    if (wid == 0)      { sg = Ahi + (size_t)bm * 128 * D2; lb = &ldsA[0][0]; }
    else if (wid == 1) { sg = Alo + (size_t)bm * 128 * D2; lb = &ldsA[1][0]; }
    else if (wid == 2) { sg = Bhi + (size_t)bn * 64 * D2;  lb = &ldsB[0][0]; }
    else               { sg = Blo + (size_t)bn * 64 * D2;  lb = &ldsB[1][0]; }
    sg += (size_t)srow * D2 + csw * 8;

    const int fr = lane & 15;
    const int ksub = lane >> 4;
    const int xs = (fr >> 1) & 3;            // per-lane read XOR (row-derived)
    const int sa = ((ksub ^ xs) << 3);       // slot byte offset/2 within row

    // A waves: 8 instrs (rows c*16..), B waves: 4 instrs. Dest linear.
    #define STAGE1(kb_) do {                                                  \
        if (wid < 2) {                                                        \
            _Pragma("unroll")                                                 \
            for (int c = 0; c < 8; ++c)                                       \
                GLDS16(sg + (size_t)c * 16 * D2 + (kb_), lb + c * 512);       \
        } else {                                                              \
            _Pragma("unroll")                                                 \
            for (int c = 0; c < 4; ++c)                                       \
                GLDS16(sg + (size_t)c * 16 * D2 + (kb_), lb + c * 512);       \
        }                                                                     \
    } while (0)

    STAGE1(0);
    __syncthreads();

    for (int kb = 0; kb < D2; kb += 32) {
        short8 ah[4], al[4], bh[2], bl[2];
        #pragma unroll
        for (int t = 0; t < 4; ++t) {
            int ra = wr * 64 + t * 16 + fr;
            ah[t] = *(const short8*)&ldsA[0][ra * 32 + sa];
            al[t] = *(const short8*)&ldsA[1][ra * 32 + sa];
        }
        #pragma unroll
        for (int t = 0; t < 2; ++t) {
            int rb = wc * 32 + t * 16 + fr;
            bh[t] = *(const short8*)&ldsB[0][rb * 32 + sa];
            bl[t] = *(const short8*)&ldsB[1][rb * 32 + sa];
        }
        __syncthreads();
        if (kb + 32 < D2) STAGE1(kb + 32);
        #pragma unroll
        for (int mt = 0; mt < 4; ++mt)
            #pragma unroll
            for (int nt = 0; nt < 2; ++nt) {
                acc[mt][nt] = __builtin_amdgcn_mfma_f32_16x16x32_bf16(ah[mt], bh[nt], acc[mt][nt], 0, 0, 0);
                acc[mt][nt] = __builtin_amdgcn_mfma_f32_16x16x32_bf16(ah[mt], bl[nt], acc[mt][nt], 0, 0, 0);
                acc[mt][nt] = __builtin_amdgcn_mfma_f32_16x16x32_bf16(al[mt], bh[nt], acc[mt][nt], 0, 0, 0);
            }
        __syncthreads();
    }
    #undef STAGE1

    float wb = Wb[0];
    #pragma unroll
    for (int mt = 0; mt < 4; ++mt) {
        int rowb = bm * 128 + wr * 64 + mt * 16 + (lane >> 4) * 4;
        float cd[4];
        #pragma unroll
        for (int r = 0; r < 4; ++r) cd[r] = cdot[rowb + r] + wb;
        #pragma unroll
        for (int nt = 0; nt < 2; ++nt) {
            int col = bn * 64 + wc * 32 + nt * 16 + fr;
            float qd = qdot[col];
            #pragma unroll
            for (int r = 0; r < 4; ++r)
                Sf[(size_t)(rowb + r) * J_ROWS + col] = acc[mt][nt][r] + cd[r] + qd;
        }
    }
}

// ------- softmax: read fp32 S row, write P hi/lo bf16 in place; m, l -------
__global__ __launch_bounds__(256) void softmax_kernel(
        float* S, float* m_out, float* l_out) {
    int t = blockIdx.x * 4 + (threadIdx.x >> 6);
    int lane = threadIdx.x & 63;
    float* rowf = S + (size_t)t * J_ROWS;
    float s[16];
    #pragma unroll
    for (int q = 0; q < 4; ++q) {
        float4 v = *(const float4*)(rowf + lane * 16 + q * 4);
        s[q * 4 + 0] = v.x; s[q * 4 + 1] = v.y;
        s[q * 4 + 2] = v.z; s[q * 4 + 3] = v.w;
    }
    float mx = s[0];
    #pragma unroll
    for (int i = 1; i < 16; ++i) mx = fmaxf(mx, s[i]);
    #pragma unroll
    for (int off = 32; off; off >>= 1) mx = fmaxf(mx, __shfl_xor(mx, off));
    float sum = 0.f;
    #pragma unroll
    for (int i = 0; i < 16; ++i) { s[i] = __expf(s[i] - mx); sum += s[i]; }
    #pragma unroll
    for (int off = 32; off; off >>= 1) sum += __shfl_xor(sum, off);
    u16x8 ph[2], pl[2];
    #pragma unroll
    for (int i = 0; i < 16; ++i) {
        u16 h, l; bsplit(s[i], h, l);
        ph[i >> 3][i & 7] = h; pl[i >> 3][i & 7] = l;
    }
    u16* rowp = (u16*)rowf;
    *(u16x8*)(rowp + lane * 16)          = ph[0];
    *(u16x8*)(rowp + lane * 16 + 8)      = ph[1];
    *(u16x8*)(rowp + 1024 + lane * 16)     = pl[0];
    *(u16x8*)(rowp + 1024 + lane * 16 + 8) = pl[1];
    if (lane == 0) { m_out[t] = mx; l_out[t] = sum; }
}

// ---------------- q2c[d] = sum_t m[t]*ctx[t,d] -----------------------------
__global__ __launch_bounds__(256) void q2c_kernel(
        const float* __restrict__ ctx, const float* __restrict__ m,
        float* __restrict__ q2c) {
    int d0 = threadIdx.x * 2;
    int tbase = blockIdx.x * 64;
    float ax = 0.f, ay = 0.f;
    for (int r = 0; r < 64; ++r) {
        int t = tbase + r;
        float b = m[t];
        float2 c = *(const float2*)(ctx + (size_t)t * D2 + d0);
        ax += b * c.x;
        ay += b * c.y;
    }
    atomicAdd(&q2c[d0], ax);
    atomicAdd(&q2c[d0 + 1], ay);
}

// ---------------- GEMM2 (MFMA split-bf16): c2q=(P@qry)/l; writes ALL of G --
// M=8192 N=512 K=1024. BM=64 BN=64, 4 waves 2x2 (wave: 32x32), BK=32.
// P rows: stride PSTR u16, hi at +0, lo at +1024 within the fp32 S row.
// grid: 1024 blocks = 4/CU, XCD-swizzled. Staging: 16 rows/instr.
__global__ __launch_bounds__(256) void gemm2_mfma(
        const u16* __restrict__ P, const u16* __restrict__ Qth,
        const u16* __restrict__ Qtl, const float* __restrict__ l_in,
        const float* __restrict__ ctx, const float* __restrict__ q2c,
        float* __restrict__ G) {
    __shared__ u16 ldsA[2][2048];   // P hi/lo:    [row=64][32k]
    __shared__ u16 ldsB[2][2048];   // qry^T hi/lo:[row=64][32k]
    const int tid = threadIdx.x;
    const int wid = tid >> 6, lane = tid & 63;
    const int wr = wid >> 1, wc = wid & 1;
    int flat = blockIdx.x;
    int s = (flat & 7) * 128 + (flat >> 3);      // 1024 blocks, bijective
    const int bn = s & 7, bm = s >> 3;

    f32x4 acc[2][2];
    #pragma unroll
    for (int mt = 0; mt < 2; ++mt)
        #pragma unroll
        for (int nt = 0; nt < 2; ++nt) acc[mt][nt] = (f32x4)0.0f;

    const int srow = lane >> 2;
    const int csw  = (lane & 3) ^ ((lane >> 3) & 3);
    const u16* sg;
    u16* lb;
    size_t lds_ld;   // source row stride (u16)
    if (wid == 0)      { sg = P + (size_t)bm * 64 * PSTR;        lds_ld = PSTR;   lb = &ldsA[0][0]; }
    else if (wid == 1) { sg = P + (size_t)bm * 64 * PSTR + 1024; lds_ld = PSTR;   lb = &ldsA[1][0]; }
    else if (wid == 2) { sg = Qth + (size_t)bn * 64 * J_ROWS;    lds_ld = J_ROWS; lb = &ldsB[0][0]; }
    else               { sg = Qtl + (size_t)bn * 64 * J_ROWS;    lds_ld = J_ROWS; lb = &ldsB[1][0]; }
    sg += (size_t)srow * lds_ld + csw * 8;

    const int fr = lane & 15;
    const int ksub = lane >> 4;
    const int xs = (fr >> 1) & 3;
    const int sa = ((ksub ^ xs) << 3);

    // every wave: 4 instrs (rows c*16..c*16+15) -> lb + c*512
    #define STAGE2(kb_) do {                                                  \
        _Pragma("unroll")                                                     \
        for (int c = 0; c < 4; ++c)                                           \
            GLDS16(sg + (size_t)c * 16 * lds_ld + (kb_), lb + c * 512);       \
    } while (0)

    STAGE2(0);
    __syncthreads();

    for (int kb = 0; kb < J_ROWS; kb += 32) {
        short8 ah[2], al[2], bh[2], bl[2];
        #pragma unroll
        for (int t = 0; t < 2; ++t) {
            int ra = wr * 32 + t * 16 + fr;
            ah[t] = *(const short8*)&ldsA[0][ra * 32 + sa];
            al[t] = *(const short8*)&ldsA[1][ra * 32 + sa];
            int rb = wc * 32 + t * 16 + fr;
            bh[t] = *(const short8*)&ldsB[0][rb * 32 + sa];
            bl[t] = *(const short8*)&ldsB[1][rb * 32 + sa];
        }
        __syncthreads();
        if (kb + 32 < J_ROWS) STAGE2(kb + 32);
        #pragma unroll
        for (int mt = 0; mt < 2; ++mt)
            #pragma unroll
            for (int nt = 0; nt < 2; ++nt) {
                acc[mt][nt] = __builtin_amdgcn_mfma_f32_16x16x32_bf16(ah[mt], bh[nt], acc[mt][nt], 0, 0, 0);
                acc[mt][nt] = __builtin_amdgcn_mfma_f32_16x16x32_bf16(ah[mt], bl[nt], acc[mt][nt], 0, 0, 0);
                acc[mt][nt] = __builtin_amdgcn_mfma_f32_16x16x32_bf16(al[mt], bh[nt], acc[mt][nt], 0, 0, 0);
            }
        __syncthreads();
    }
    #undef STAGE2

    #pragma unroll
    for (int mt = 0; mt < 2; ++mt) {
        int rowb = bm * 64 + wr * 32 + mt * 16 + (lane >> 4) * 4;
        float rl4[4];
        #pragma unroll
        for (int r = 0; r < 4; ++r) rl4[r] = 1.0f / l_in[rowb + r];
        #pragma unroll
        for (int nt = 0; nt < 2; ++nt) {
            int d = bn * 64 + wc * 32 + nt * 16 + fr;
            float qc = q2c[d];
            #pragma unroll
            for (int r = 0; r < 4; ++r) {
                int row = rowb + r;
                float v = acc[mt][nt][r] * rl4[r];
                float c = ctx[(size_t)row * D2 + d];
                float* gr = G + (size_t)row * G_LD;
                gr[d] = c;
                gr[512 + d] = v;
                gr[1024 + d] = c * v;
                gr[1536 + d] = c * qc;
            }
        }
    }
}

extern "C" void kernel_launch(void* const* d_in, const int* in_sizes, int n_in,
                              void* d_out, int out_size, void* d_ws, size_t ws_size,
                              hipStream_t stream) {
    const float* ctx = (const float*)d_in[0];
    const float* qry = (const float*)d_in[1];
    const float* Ww  = (const float*)d_in[2];
    const float* Wb  = (const float*)d_in[3];
    float* G = (float*)d_out;

    const size_t MB = 1ull << 20;
    char* p = (char*)d_ws;
    float* Sf = (float*)p; p += 32 * MB;  // S fp32; later P hi/lo in place
    u16* ctxh = (u16*)p; p += 8 * MB;
    u16* ctxl = (u16*)p; p += 8 * MB;
    u16* qmh  = (u16*)p; p += 1 * MB;     // (qry*wm) hi, [J][D2]
    u16* qml  = (u16*)p; p += 1 * MB;
    u16* qth  = (u16*)p; p += 1 * MB;     // qry^T hi, [D2][J]
    u16* qtl  = (u16*)p; p += 1 * MB;
    float* cdot = (float*)p; p += T_ROWS * 4;
    float* qdot = (float*)p; p += J_ROWS * 4;
    float* mrow = (float*)p; p += T_ROWS * 4;
    float* lrow = (float*)p; p += T_ROWS * 4;
    float* q2c  = (float*)p; p += D2 * 4;

    (void)hipMemsetAsync(q2c, 0, D2 * sizeof(float), stream);

    split_ctx_kernel<<<T_ROWS / 4, 256, 0, stream>>>(ctx, Ww, ctxh, ctxl, cdot);
    split_q_kernel<<<dim3(J_ROWS / 32, D2 / 32), 256, 0, stream>>>(qry, Ww, qmh, qml, qth, qtl);
    qdot_kernel<<<J_ROWS / 4, 256, 0, stream>>>(qry, Ww, qdot);

    gemm1_mfma<<<1024, 256, 0, stream>>>(ctxh, ctxl, qmh, qml, cdot, qdot, Wb, Sf);
    softmax_kernel<<<T_ROWS / 4, 256, 0, stream>>>(Sf, mrow, lrow);
    q2c_kernel<<<T_ROWS / 64, 256, 0, stream>>>(ctx, mrow, q2c);
    gemm2_mfma<<<1024, 256, 0, stream>>>((u16*)Sf, qth, qtl, lrow, ctx, q2c, G);
}